// Round 18
// baseline (569.933 us; speedup 1.0000x reference)
//
#include <hip/hip_runtime.h>
#include <stdint.h>

// W8A16 quantized linear, two-phase:
//   Pre-pass: A f32->f16 (64 MB), W = fp16(q*scale) (32 MB) into d_ws.
//   GEMM: TWO INDEPENDENT BLOCKS PER CU (the untried lever).
//     R5-R17 all ran 1 block/CU: every barrier stall exposed 100%.
//     m114: independent waves overlap MFMA & memory fully — so run 2
//     blocks/CU and let block B's MFMA hide block A's LDS/barrier time.
//     Block: 256x128 tile, BK=32, 4 waves (2M x 2N), wave tile 128x64
//     (acc[8][4] AGPR), LDS 48 KB (A 2x16KB + B 2x8KB), single barrier
//     per K-tile, compiler-managed lgkm (m97: it interleaves ds_read
//     with MFMA near-optimally). Occupancy capped at 2 blocks/CU by both
//     LDS (160/48) and regs (128 AGPR + ~90 arch -> 2 waves/SIMD).
//   Layout machinery identical to R13/R17 (HW-verified, 0 conflicts):
//     packed-pair XOR LDS map, inverse-swizzled gload_lds source,
//     aoff/boff + 2048*frag immediates.
// Race ledger (R7-verified logic): reads of buf(kt) complete before
//   TILE(kt)'s MFMAs (lgkm deps); end-of-tile barrier seals block-wide;
//   buf(kt) is overwritten during TILE(kt+1) (stages kt+2) — after the
//   barrier. Stage->use: issued tile top, VMW(0)+barrier at tile end,
//   ~1 tile slack >= HBM latency.

#define M_DIM 8192
#define N_DIM 4096
#define K_DIM 4096
#define BM 256
#define BN 128
#define BK 32
#define NKT (K_DIM / BK)   // 128 K-tiles

typedef _Float16 f16;
typedef f16 f16x8 __attribute__((ext_vector_type(8)));
typedef f16 f16x2 __attribute__((ext_vector_type(2)));
typedef float f32x4 __attribute__((ext_vector_type(4)));

static __device__ __forceinline__ f16x2 cvt2(float a, float b) {
  return __builtin_bit_cast(f16x2, __builtin_amdgcn_cvt_pkrtz(a, b));
}

// ---------------- pre-pass kernels ----------------

__global__ __launch_bounds__(256) void conv_a_kernel(
    const float* __restrict__ A, f16* __restrict__ Af)
{
  const size_t stride = (size_t)gridDim.x * blockDim.x;
  size_t i = (size_t)blockIdx.x * blockDim.x + threadIdx.x;
  const size_t n8 = (size_t)M_DIM * K_DIM / 8;
  for (; i < n8; i += stride) {
    const f32x4* p = (const f32x4*)(A + i * 8);
    f32x4 v0 = p[0], v1 = p[1];
    f16x2 a = cvt2(v0.x, v0.y), b = cvt2(v0.z, v0.w);
    f16x2 c = cvt2(v1.x, v1.y), d = cvt2(v1.z, v1.w);
    *(f16x8*)(Af + i * 8) = (f16x8){a.x, a.y, b.x, b.y, c.x, c.y, d.x, d.y};
  }
}

__global__ __launch_bounds__(256) void conv_b_kernel(
    const int* __restrict__ Qw, const float* __restrict__ Sc,
    f16* __restrict__ Wf)
{
  const int o = blockIdx.x;
  const int t = threadIdx.x;
  const float s = Sc[o];
  const int* q = Qw + (size_t)o * K_DIM + t * 16;
  f16* w = Wf + (size_t)o * K_DIM + t * 16;
  #pragma unroll
  for (int h = 0; h < 2; ++h) {
    int4 u0 = *(const int4*)(q + h * 8);
    int4 u1 = *(const int4*)(q + h * 8 + 4);
    f16x2 a = cvt2((float)u0.x * s, (float)u0.y * s);
    f16x2 b = cvt2((float)u0.z * s, (float)u0.w * s);
    f16x2 c = cvt2((float)u1.x * s, (float)u1.y * s);
    f16x2 d = cvt2((float)u1.z * s, (float)u1.w * s);
    *(f16x8*)(w + h * 8) = (f16x8){a.x, a.y, b.x, b.y, c.x, c.y, d.x, d.y};
  }
}

// ---------------- main GEMM ----------------

#define BARX() __builtin_amdgcn_s_barrier()
#define SCHED0() __builtin_amdgcn_sched_barrier(0)
#define VMW0() asm volatile("s_waitcnt vmcnt(0)" ::: "memory")

// stage A tile (256x32 f16 = 16 KB): 4 x global_load_lds(16B)/thread.
// chunk i covers rows 64i..64i+63; thread t: line=t>>3, phys slot p=t&7,
// logical x=p^(line&7): row=(32i+line)*2+(x>>2), k-slot x&3.
#define STAGE_A(bi, ktn) do { \
  _Pragma("unroll") \
  for (int _i = 0; _i < 4; ++_i) { \
    const f16* _g = aSrc + (size_t)((32 * _i + st_R) * 2 + st_h) * K_DIM \
                    + (ktn) * BK + st_s * 8; \
    char* _l = (char*)&As[bi][0] + _i * 4096 + wid * 1024; \
    __builtin_amdgcn_global_load_lds( \
        (const __attribute__((address_space(1))) void*)_g, \
        (__attribute__((address_space(3))) void*)_l, 16, 0, 0); \
  } } while (0)

// stage B tile (128x32 f16 = 8 KB): 2 chunks
#define STAGE_B(bi, ktn) do { \
  _Pragma("unroll") \
  for (int _i = 0; _i < 2; ++_i) { \
    const f16* _g = bSrc + (size_t)((32 * _i + st_R) * 2 + st_h) * K_DIM \
                    + (ktn) * BK + st_s * 8; \
    char* _l = (char*)&Bs[bi][0] + _i * 4096 + wid * 1024; \
    __builtin_amdgcn_global_load_lds( \
        (const __attribute__((address_space(1))) void*)_g, \
        (__attribute__((address_space(3))) void*)_l, 16, 0, 0); \
  } } while (0)

// fragment reads: base + compile-time 2048*frag immediates (R13-verified)
#define A_LDS(CB, j) (const f16x8*)((const char*)&As[CB][0] + aoff + 2048 * (j))
#define B_LDS(CB, n) (const f16x8*)((const char*)&Bs[CB][0] + boff + 2048 * (n))

// One K-tile: stage kt+1 into NXT, read CUR, 32 MFMA (one per acc), seal.
#define TILE(KT, CUR, NXT, M1) do { \
  if (M1) { STAGE_A(NXT, (KT) + 1); STAGE_B(NXT, (KT) + 1); } \
  af[0] = *A_LDS(CUR, 0); af[1] = *A_LDS(CUR, 1); \
  af[2] = *A_LDS(CUR, 2); af[3] = *A_LDS(CUR, 3); \
  af[4] = *A_LDS(CUR, 4); af[5] = *A_LDS(CUR, 5); \
  af[6] = *A_LDS(CUR, 6); af[7] = *A_LDS(CUR, 7); \
  bf[0] = *B_LDS(CUR, 0); bf[1] = *B_LDS(CUR, 1); \
  bf[2] = *B_LDS(CUR, 2); bf[3] = *B_LDS(CUR, 3); \
  _Pragma("unroll") \
  for (int _m = 0; _m < 8; ++_m) \
    _Pragma("unroll") \
    for (int _n = 0; _n < 4; ++_n) \
      acc[_m][_n] = __builtin_amdgcn_mfma_f32_16x16x32_f16( \
          af[_m], bf[_n], acc[_m][_n], 0, 0, 0); \
  VMW0(); \
  BARX(); \
} while (0)

__global__ __launch_bounds__(256, 1) void w8a16_gemm_f16_kernel(
    const f16* __restrict__ Af,   // [M][K]
    const f16* __restrict__ Wf,   // [N][K], scale folded
    float* __restrict__ Out)      // [M][N]
{
  __shared__ __align__(16) f16 As[2][BM * BK];  // 2 x 16 KB
  __shared__ __align__(16) f16 Bs[2][BN * BK];  // 2 x 8 KB  -> 48 KB total

  const int t    = threadIdx.x;
  const int lane = t & 63;
  const int wid  = t >> 6;       // 0..3
  const int wm   = wid >> 1;     // 0..1 (M interleave)
  const int wn   = wid & 1;      // 0..1 (N interleave)
  const int fr   = lane & 15;
  const int qk   = lane >> 4;    // k-slot 0..3

  const int st_R = t >> 3;                    // 0..31
  const int st_x = (t & 7) ^ (st_R & 7);
  const int st_h = st_x >> 2;
  const int st_s = st_x & 3;

  // A frag j: rows (2j+wm)*16+fr, +32 rows/frag -> +2048 B (XOR j-invariant)
  const int ca   = wm * 16 + fr;
  const int aoff = (ca >> 1) * 128
                 + (((((ca & 1) << 2) | qk) ^ ((ca >> 1) & 7)) << 4);
  // B frag n: rows (2n+wn)*16+fr, +2048 B/frag
  const int cb   = wn * 16 + fr;
  const int boff = (cb >> 1) * 128
                 + (((((cb & 1) << 2) | qk) ^ ((cb >> 1) & 7)) << 4);

  // XCD swizzle: 1024 blocks (%8==0 -> simple form); consecutive swz on an
  // XCD share tn (1 MB B panel L2-pinned) while tm sweeps.
  const int bid = blockIdx.x;
  const int swz = (bid & 7) * 128 + (bid >> 3);
  const int tm  = swz & 31;      // 32 M-tiles
  const int tn  = swz >> 5;      // 32 N-tiles

  const f16* aSrc = Af + (size_t)tm * BM * K_DIM;   // block-uniform -> SGPR
  const f16* bSrc = Wf + (size_t)tn * BN * K_DIM;

  f32x4 acc[8][4] = {};
  f16x8 af[8], bf[4];

  // prologue
  STAGE_A(0, 0);
  STAGE_B(0, 0);
  VMW0();
  BARX();
  SCHED0();

  // hot loop: 63 branch-free pairs (kt = 0..125)
  for (int kt = 0; kt < NKT - 2; kt += 2) {
    TILE(kt,     0, 1, 1);
    TILE(kt + 1, 1, 0, 1);
  }
  TILE(NKT - 2, 0, 1, 1);
  TILE(NKT - 1, 1, 0, 0);

  // epilogue: C/D col = lane&15, row = (lane>>4)*4 + reg
  const int fq = lane >> 4;
  #pragma unroll
  for (int mi = 0; mi < 8; ++mi) {
    const size_t row = (size_t)tm * BM + (2 * mi + wm) * 16 + fq * 4;
    #pragma unroll
    for (int ni = 0; ni < 4; ++ni) {
      const size_t col = (size_t)tn * BN + (2 * ni + wn) * 16 + fr;
      #pragma unroll
      for (int r = 0; r < 4; ++r)
        Out[(row + r) * N_DIM + col] = acc[mi][ni][r];
    }
  }
}

// ---------------- fallback (round-3 verified path) ----------------

__global__ __launch_bounds__(256) void w8a16_gemm_fb_kernel(
    const float* __restrict__ A, const int* __restrict__ Qw,
    const float* __restrict__ Sc, float* __restrict__ Out)
{
  __shared__ __align__(16) float Asf[2][128 * 32];
  __shared__ __align__(16) f16 Bsf[2][128][32];

  const int t = threadIdx.x, lane = t & 63, wid = t >> 6;
  const int wr = wid >> 1, wc = wid & 1;
  const int nwg = gridDim.x, cpx = nwg >> 3, bid = blockIdx.x;
  const int swz = (bid & 7) * cpx + (bid >> 3);
  const int tn = swz & 31, tm = swz >> 5;
  const size_t a_base = (size_t)tm * 128 * K_DIM;
  const size_t b_base = (size_t)tn * 128 * K_DIM;
  f32x4 acc[4][4] = {};
  const int a_r = t >> 3;
  const int a_slog = (t & 7) ^ ((t >> 3) & 7);

  auto stageA = [&](int buf, int kt) {
    #pragma unroll
    for (int c = 0; c < 4; ++c) {
      const float* g = A + a_base + (size_t)(c * 32 + a_r) * K_DIM + kt * 32 + a_slog * 4;
      char* l = (char*)&Asf[buf][0] + c * 4096 + wid * 1024;
      __builtin_amdgcn_global_load_lds(
          (const __attribute__((address_space(1))) void*)g,
          (__attribute__((address_space(3))) void*)l, 16, 0, 0);
    }
  };
  const int b_r = t >> 3, b_col = (t & 7) * 4;
  auto loadB = [&](int kt, int4* v) {
    #pragma unroll
    for (int c = 0; c < 4; ++c)
      v[c] = *(const int4*)(Qw + b_base + (size_t)(c * 32 + b_r) * K_DIM + kt * 32 + b_col);
  };
  auto writeB = [&](int buf, const int4* v) {
    #pragma unroll
    for (int c = 0; c < 4; ++c) {
      f16x2 lo = cvt2((float)v[c].x, (float)v[c].y);
      f16x2 hi = cvt2((float)v[c].z, (float)v[c].w);
      *(f16x2*)&Bsf[buf][c * 32 + b_r][b_col] = lo;
      *(f16x2*)&Bsf[buf][c * 32 + b_r][b_col + 2] = hi;
    }
  };
  auto compute = [&](int buf) {
    const int fr2 = lane & 15, q = lane >> 4;
    f16x8 af2[4], bf2[4];
    #pragma unroll
    for (int i = 0; i < 4; ++i) {
      const int r = wr * 64 + i * 16 + fr2;
      const float* base = &Asf[buf][0] + r * 32;
      const int s0 = q * 2;
      f32x4 a0 = *(const f32x4*)(base + ((s0 ^ (r & 7)) * 4));
      f32x4 a1 = *(const f32x4*)(base + (((s0 + 1) ^ (r & 7)) * 4));
      f16x2 p0 = cvt2(a0.x, a0.y), p1 = cvt2(a0.z, a0.w);
      f16x2 p2 = cvt2(a1.x, a1.y), p3 = cvt2(a1.z, a1.w);
      af2[i] = (f16x8){p0.x, p0.y, p1.x, p1.y, p2.x, p2.y, p3.x, p3.y};
      bf2[i] = *(const f16x8*)&Bsf[buf][wc * 64 + i * 16 + fr2][q * 8];
    }
    #pragma unroll
    for (int mi = 0; mi < 4; ++mi)
      #pragma unroll
      for (int ni = 0; ni < 4; ++ni)
        acc[mi][ni] = __builtin_amdgcn_mfma_f32_16x16x32_f16(
            af2[mi], bf2[ni], acc[mi][ni], 0, 0, 0);
  };

  { int4 b0[4]; stageA(0, 0); loadB(0, b0); writeB(0, b0); }
  __syncthreads();
  for (int kt = 0; kt < K_DIM / 32; ++kt) {
    const int buf = kt & 1;
    const bool more = (kt + 1) < K_DIM / 32;
    int4 nb[4];
    if (more) { stageA(buf ^ 1, kt + 1); loadB(kt + 1, nb); }
    compute(buf);
    if (more) writeB(buf ^ 1, nb);
    __syncthreads();
  }
  const int fr2 = lane & 15, fq = lane >> 4;
  const int cb = tn * 128 + wc * 64 + fr2;
  const int rb = tm * 128 + wr * 64 + fq * 4;
  #pragma unroll
  for (int ni = 0; ni < 4; ++ni) {
    const float s = Sc[cb + ni * 16];
    #pragma unroll
    for (int mi = 0; mi < 4; ++mi)
      #pragma unroll
      for (int r = 0; r < 4; ++r)
        Out[(size_t)(rb + mi * 16 + r) * N_DIM + (cb + ni * 16)] =
            acc[mi][ni][r] * s;
  }
}

extern "C" void kernel_launch(void* const* d_in, const int* in_sizes, int n_in,
                              void* d_out, int out_size, void* d_ws, size_t ws_size,
                              hipStream_t stream) {
  const float* A  = (const float*)d_in[0];
  const int*   Qw = (const int*)d_in[1];
  const float* Sc = (const float*)d_in[2];
  float*       Out = (float*)d_out;

  const size_t a_bytes = (size_t)M_DIM * K_DIM * sizeof(f16);  // 64 MB
  const size_t w_bytes = (size_t)N_DIM * K_DIM * sizeof(f16);  // 32 MB

  if (ws_size >= a_bytes + w_bytes) {
    f16* Af = (f16*)d_ws;
    f16* Wf = (f16*)((char*)d_ws + a_bytes);
    conv_a_kernel<<<2048, 256, 0, stream>>>(A, Af);
    conv_b_kernel<<<N_DIM, 256, 0, stream>>>(Qw, Sc, Wf);
    dim3 grid((M_DIM / BM) * (N_DIM / BN));  // 32*32 = 1024 blocks
    w8a16_gemm_f16_kernel<<<grid, 256, 0, stream>>>(Af, Wf, Out);
  } else {
    dim3 grid((M_DIM / 128) * (N_DIM / 128));
    w8a16_gemm_fb_kernel<<<grid, 256, 0, stream>>>(A, Qw, Sc, Out);
  }
}